// Round 1
// baseline (12803.004 us; speedup 1.0000x reference)
//
#include <hip/hip_runtime.h>
#include <math.h>

#define BB 64
#define SS 64
#define HH 512
#define VV 32000
#define TT 80

__global__ __launch_bounds__(256) void init_kernel(float* __restrict__ h0, int* __restrict__ tok) {
    int i = blockIdx.x * 256 + threadIdx.x;
    if (i < BB * HH) h0[i] = 0.0f;
    if (i < BB) tok[i] = 0;   // SOS_IDX = 0
}

// GRU cell: h_out = GRUCell(h_in, emb[tok[b]]) ; grid (32 j-tiles, 4 b-tiles), 256 thr
// thread = (bl = tid&15, jl = tid>>4): 16 b x 16 j per block, 6 dot-products/thread
__global__ __launch_bounds__(256) void gru_step(
    const float* __restrict__ emb, const int* __restrict__ tok, int tok_stride,
    const float* __restrict__ h_in, float* __restrict__ h_out,
    const float* __restrict__ Wih, const float* __restrict__ Whh,
    const float* __restrict__ bih, const float* __restrict__ bhh)
{
    const int tid = threadIdx.x;
    const int bl = tid & 15;
    const int jl = tid >> 4;
    const int j0 = blockIdx.x * 16;
    const int b0 = blockIdx.y * 16;
    const int j = j0 + jl;
    const int b = b0 + bl;

    __shared__ float x_s[16][132];   // pad 132: 4*bl bank offset, float4-aligned
    __shared__ float h_s[16][132];

    float air = 0.f, aiz = 0.f, ain = 0.f, ahr = 0.f, ahz = 0.f, ahn = 0.f;

    const float* __restrict__ Wr = Wih + (size_t)j * HH;
    const float* __restrict__ Wz = Wih + (size_t)(j + HH) * HH;
    const float* __restrict__ Wn = Wih + (size_t)(j + 2 * HH) * HH;
    const float* __restrict__ Ur = Whh + (size_t)j * HH;
    const float* __restrict__ Uz = Whh + (size_t)(j + HH) * HH;
    const float* __restrict__ Un = Whh + (size_t)(j + 2 * HH) * HH;

    for (int k0 = 0; k0 < HH; k0 += 128) {
        #pragma unroll
        for (int i = 0; i < 2; ++i) {
            int f = tid + i * 256;        // float4 id in [0,512)
            int row = f >> 5;             // 32 float4 per 128-wide row
            int col = (f & 31) << 2;
            int tkb = tok[(size_t)(b0 + row) * tok_stride];
            *(float4*)&x_s[row][col] = *(const float4*)&emb[(size_t)tkb * HH + k0 + col];
            *(float4*)&h_s[row][col] = *(const float4*)&h_in[(size_t)(b0 + row) * HH + k0 + col];
        }
        __syncthreads();
        #pragma unroll 8
        for (int kk = 0; kk < 128; kk += 4) {
            float4 xv = *(const float4*)&x_s[bl][kk];
            float4 hv = *(const float4*)&h_s[bl][kk];
            float4 w;
            w = *(const float4*)&Wr[k0 + kk]; air += w.x*xv.x + w.y*xv.y + w.z*xv.z + w.w*xv.w;
            w = *(const float4*)&Wz[k0 + kk]; aiz += w.x*xv.x + w.y*xv.y + w.z*xv.z + w.w*xv.w;
            w = *(const float4*)&Wn[k0 + kk]; ain += w.x*xv.x + w.y*xv.y + w.z*xv.z + w.w*xv.w;
            w = *(const float4*)&Ur[k0 + kk]; ahr += w.x*hv.x + w.y*hv.y + w.z*hv.z + w.w*hv.w;
            w = *(const float4*)&Uz[k0 + kk]; ahz += w.x*hv.x + w.y*hv.y + w.z*hv.z + w.w*hv.w;
            w = *(const float4*)&Un[k0 + kk]; ahn += w.x*hv.x + w.y*hv.y + w.z*hv.z + w.w*hv.w;
        }
        __syncthreads();
    }

    float ir = air + bih[j];
    float iz = aiz + bih[j + HH];
    float in_ = ain + bih[j + 2 * HH];
    float hr = ahr + bhh[j];
    float hz = ahz + bhh[j + HH];
    float hn = ahn + bhh[j + 2 * HH];
    float r = 1.0f / (1.0f + expf(-(ir + hr)));
    float z = 1.0f / (1.0f + expf(-(iz + hz)));
    float n = tanhf(in_ + r * hn);
    float hold = h_in[(size_t)b * HH + j];
    h_out[(size_t)b * HH + j] = (1.0f - z) * n + z * hold;
}

// FC: out[b, t, v] = h[b] . fcW[v] + fcb[v]. Tile 64b x 64v, K chunks of 64.
// LDS tiles stored TRANSPOSED (w_s[k][v], h_s[k][b]) -> inner loop = 2x ds_read_b128 + 16 FMA.
__global__ __launch_bounds__(256) void fc_kernel(
    const float* __restrict__ h, const float* __restrict__ fcW,
    const float* __restrict__ fcb, float* __restrict__ out, int t)
{
    const int tid = threadIdx.x;
    const int tv = tid & 15;
    const int tb = tid >> 4;
    const int v0 = blockIdx.x * 64;

    __shared__ float w_s[64][68];   // [k][v], pad 68 keeps float4 align + <=2-way banks
    __shared__ float h_s[64][68];   // [k][b]

    float acc[4][4];
    #pragma unroll
    for (int i = 0; i < 4; ++i)
        #pragma unroll
        for (int j2 = 0; j2 < 4; ++j2) acc[i][j2] = 0.f;

    for (int k0 = 0; k0 < HH; k0 += 64) {
        #pragma unroll
        for (int i = 0; i < 4; ++i) {
            int f = tid + i * 256;       // float4 id in [0,1024)
            int row = f >> 4;            // v (or b) row in [0,64)
            int kc = (f & 15) << 2;      // k within chunk
            float4 wv = *(const float4*)&fcW[(size_t)(v0 + row) * HH + k0 + kc];
            w_s[kc + 0][row] = wv.x; w_s[kc + 1][row] = wv.y;
            w_s[kc + 2][row] = wv.z; w_s[kc + 3][row] = wv.w;
            float4 hv = *(const float4*)&h[(size_t)row * HH + k0 + kc];
            h_s[kc + 0][row] = hv.x; h_s[kc + 1][row] = hv.y;
            h_s[kc + 2][row] = hv.z; h_s[kc + 3][row] = hv.w;
        }
        __syncthreads();
        #pragma unroll 8
        for (int kk = 0; kk < 64; ++kk) {
            float4 wv = *(const float4*)&w_s[kk][tv << 2];
            float4 hv = *(const float4*)&h_s[kk][tb << 2];
            acc[0][0] += hv.x * wv.x; acc[0][1] += hv.x * wv.y; acc[0][2] += hv.x * wv.z; acc[0][3] += hv.x * wv.w;
            acc[1][0] += hv.y * wv.x; acc[1][1] += hv.y * wv.y; acc[1][2] += hv.y * wv.z; acc[1][3] += hv.y * wv.w;
            acc[2][0] += hv.z * wv.x; acc[2][1] += hv.z * wv.y; acc[2][2] += hv.z * wv.z; acc[2][3] += hv.z * wv.w;
            acc[3][0] += hv.w * wv.x; acc[3][1] += hv.w * wv.y; acc[3][2] += hv.w * wv.z; acc[3][3] += hv.w * wv.w;
        }
        __syncthreads();
    }

    float4 bias = *(const float4*)&fcb[v0 + (tv << 2)];
    #pragma unroll
    for (int bi = 0; bi < 4; ++bi) {
        int b = (tb << 2) + bi;
        float4 o;
        o.x = acc[bi][0] + bias.x;
        o.y = acc[bi][1] + bias.y;
        o.z = acc[bi][2] + bias.z;
        o.w = acc[bi][3] + bias.w;
        *(float4*)&out[(size_t)b * (TT * VV) + (size_t)t * VV + v0 + (tv << 2)] = o;
    }
}

// First-index argmax over V per batch row via monotone float->uint packing.
__global__ __launch_bounds__(256) void argmax_kernel(
    const float* __restrict__ out, int t, int* __restrict__ tok_next)
{
    const int b = blockIdx.x;
    const float* __restrict__ row = out + (size_t)b * (TT * VV) + (size_t)t * VV;
    unsigned long long best = 0ull;
    for (int v = threadIdx.x; v < VV; v += 256) {
        unsigned u = __float_as_uint(row[v]);
        unsigned m = (u & 0x80000000u) ? ~u : (u | 0x80000000u);
        unsigned long long p = ((unsigned long long)m << 32) |
                               (unsigned long long)(0xFFFFFFFFu - (unsigned)v);
        best = p > best ? p : best;   // equal value -> smaller v wins (first-index, numpy semantics)
    }
    __shared__ unsigned long long red[256];
    red[threadIdx.x] = best;
    __syncthreads();
    for (int s2 = 128; s2 > 0; s2 >>= 1) {
        if (threadIdx.x < s2) {
            unsigned long long o = red[threadIdx.x + s2];
            if (o > red[threadIdx.x]) red[threadIdx.x] = o;
        }
        __syncthreads();
    }
    if (threadIdx.x == 0)
        tok_next[b] = (int)(0xFFFFFFFFu - (unsigned)(red[0] & 0xFFFFFFFFull));
}

extern "C" void kernel_launch(void* const* d_in, const int* in_sizes, int n_in,
                              void* d_out, int out_size, void* d_ws, size_t ws_size,
                              hipStream_t stream) {
    const int*   src   = (const int*)  d_in[0];
    const float* emb   = (const float*)d_in[1];
    const float* eWih  = (const float*)d_in[2];
    const float* eWhh  = (const float*)d_in[3];
    const float* ebih  = (const float*)d_in[4];
    const float* ebhh  = (const float*)d_in[5];
    const float* dWih  = (const float*)d_in[6];
    const float* dWhh  = (const float*)d_in[7];
    const float* dbih  = (const float*)d_in[8];
    const float* dbhh  = (const float*)d_in[9];
    const float* fcW   = (const float*)d_in[10];
    const float* fcb   = (const float*)d_in[11];
    float* out = (float*)d_out;

    float* hA  = (float*)d_ws;              // [64,512]
    float* hB  = hA + BB * HH;              // [64,512]
    int*   tok = (int*)(hB + BB * HH);      // [81,64]

    hipLaunchKernelGGL(init_kernel, dim3(128), dim3(256), 0, stream, hA, tok);

    const float* hin = hA;
    float* hout = hB;

    // ---- encoder: token for b at time t is src[b*64 + t] (stride 64) ----
    for (int t = 0; t < SS; ++t) {
        hipLaunchKernelGGL(gru_step, dim3(32, 4), dim3(256), 0, stream,
                           emb, src + t, SS, hin, hout, eWih, eWhh, ebih, ebhh);
        float* tmp = (float*)hin; hin = hout; hout = tmp;
    }

    // ---- decoder ----
    for (int t = 0; t < TT; ++t) {
        hipLaunchKernelGGL(gru_step, dim3(32, 4), dim3(256), 0, stream,
                           emb, tok + t * BB, 1, hin, hout, dWih, dWhh, dbih, dbhh);
        float* tmp = (float*)hin; hin = hout; hout = tmp;
        hipLaunchKernelGGL(fc_kernel, dim3(500), dim3(256), 0, stream,
                           hin, fcW, fcb, out, t);
        hipLaunchKernelGGL(argmax_kernel, dim3(64), dim3(256), 0, stream,
                           out, t, tok + (t + 1) * BB);
    }
}